// Round 1
// baseline (631.410 us; speedup 1.0000x reference)
//
#include <hip/hip_runtime.h>
#include <hip/hip_bf16.h>

#define NN 256
#define MM 128
#define DS 384
#define DP 128
#define CC 22
#define C2 484   // 22*22

// output layout: eij [256*256*484], ei [256*22], logits [128*256*22]
#define OUT_EIJ 0
#define OUT_EI  (NN*NN*C2)          // 31719424
#define OUT_LOG (OUT_EI + NN*CC)    // 31725056

// ---------------------------------------------------------------------------
// Kernel 1: single branch. h = GELU(single@w1+b1); ei = LN(h)@w2 + b2
// grid 256 (one row n), block 384
// ---------------------------------------------------------------------------
__global__ __launch_bounds__(384) void k_single(
    const float* __restrict__ single, const float* __restrict__ w1,
    const float* __restrict__ b1, const float* __restrict__ g1,
    const float* __restrict__ be1, const float* __restrict__ w2,
    const float* __restrict__ b2, float* __restrict__ out_ei)
{
  __shared__ float srow[DS];
  __shared__ float hl[DS];
  __shared__ float part[16*CC];
  __shared__ float wred[8], wredq[8], mur[2];
  int n = blockIdx.x, t = threadIdx.x;
  srow[t] = single[n*DS + t];
  __syncthreads();
  float acc = b1[t];
  for (int d = 0; d < DS; ++d) acc = fmaf(srow[d], w1[d*DS + t], acc);
  // exact GELU: 0.5*x*(1+erf(x/sqrt(2)))
  float hv = 0.5f * acc * (1.0f + erff(acc * 0.70710678118654752f));
  // LN over 384 (block reduce)
  float s = hv, q = hv*hv;
  for (int off = 32; off; off >>= 1) { s += __shfl_down(s, off); q += __shfl_down(q, off); }
  int wv = t >> 6, ln = t & 63;
  if (ln == 0) { wred[wv] = s; wredq[wv] = q; }
  __syncthreads();
  if (t == 0) {
    float S = 0.f, Q = 0.f;
    for (int w = 0; w < 6; ++w) { S += wred[w]; Q += wredq[w]; }
    float mu = S / (float)DS;
    float var = Q / (float)DS - mu*mu;
    mur[0] = mu; mur[1] = rsqrtf(var + 1e-5f);
  }
  __syncthreads();
  hl[t] = (hv - mur[0]) * mur[1] * g1[t] + be1[t];
  __syncthreads();
  // ei[n,c] = sum_k hl[k]*w2[k,c] + b2[c]; 16 groups x 22 classes
  if (t < 16*CC) {
    int g = t / CC, c = t % CC;
    float p = 0.f;
    for (int k = g*24; k < g*24 + 24; ++k) p = fmaf(hl[k], w2[k*CC + c], p);
    part[t] = p;
  }
  __syncthreads();
  if (t < CC) {
    float sm = b2[t];
    for (int g = 0; g < 16; ++g) sm += part[g*CC + t];
    out_ei[n*CC + t] = sm;
  }
}

// ---------------------------------------------------------------------------
// transpose msa [128,256] -> msa_t [256,128] for coalesced column staging
// ---------------------------------------------------------------------------
__global__ void k_transpose_msa(const int* __restrict__ msa, int* __restrict__ msa_t) {
  int j = blockIdx.x, m = threadIdx.x;   // 256 blocks x 128 threads
  msa_t[j*MM + m] = msa[m*NN + j];
}

// ---------------------------------------------------------------------------
// init logits[m,i,c] = ei[i,c]   (720896 elements; idx % 5632 == i*22+c)
// ---------------------------------------------------------------------------
__global__ void k_init_logits(const float* __restrict__ ei, float* __restrict__ out_log) {
  int idx = blockIdx.x*256 + threadIdx.x;
  if (idx < MM*NN*CC) out_log[idx] = ei[idx % (NN*CC)];
}

// ---------------------------------------------------------------------------
// Kernel 2: pair branch. zsym -> LN -> @w3 + b3 -> relu -> zero diag -> eij
// grid (16 j-tiles, 256 i), block 256. Each block: 16 rows x 484 cols.
// ---------------------------------------------------------------------------
__global__ __launch_bounds__(256) void k_pair(
    const float* __restrict__ pair, const float* __restrict__ g2,
    const float* __restrict__ be2, const float* __restrict__ w3,
    const float* __restrict__ b3, float* __restrict__ out_eij)
{
  __shared__ __align__(16) float z[16*DP];       // 8KB; becomes zln in-place
  __shared__ float4 w3s[16*121 + 16];            // 16 k-rows x 121 f4 (+pad for lanes 121..127)
  __shared__ float redm[256], redq[256];
  __shared__ float muA[16], rsA[16];
  int i = blockIdx.y, j0 = blockIdx.x * 16, t = threadIdx.x;

  // stage zsym = 0.5*(pair[i,j,:] + pair[j,i,:]) for 16 rows
  if (t < 128) {
    for (int jj = 0; jj < 16; ++jj) {
      float a = pair[(i*NN + (j0+jj))*DP + t];
      float b = pair[((j0+jj)*NN + i)*DP + t];
      z[jj*DP + t] = 0.5f*(a+b);
    }
  }
  __syncthreads();
  // per-row LN stats: 16 rows x 16 partials of 8 elems
  {
    int jj = t >> 4, s4 = t & 15;
    float ps = 0.f, pq = 0.f;
    for (int dd = 0; dd < 8; ++dd) { float v = z[jj*DP + s4*8 + dd]; ps += v; pq += v*v; }
    redm[t] = ps; redq[t] = pq;
  }
  __syncthreads();
  if (t < 16) {
    float S = 0.f, Q = 0.f;
    for (int ss = 0; ss < 16; ++ss) { S += redm[t*16+ss]; Q += redq[t*16+ss]; }
    float mu = S / (float)DP;
    float var = Q / (float)DP - mu*mu;
    muA[t] = mu; rsA[t] = rsqrtf(var + 1e-5f);
  }
  __syncthreads();
  for (int idx = t; idx < 16*DP; idx += 256) {
    int jj = idx >> 7, d = idx & 127;
    z[idx] = (z[idx] - muA[jj]) * rsA[jj] * g2[d] + be2[d];
  }
  __syncthreads();

  // GEMM: [16 x 128] @ [128 x 484]; thread (tr,tc): rows tr*8+rr, cols 4*tc+cc
  int tc = t & 127, tr = t >> 7;
  float acc[8][4];
  #pragma unroll
  for (int rr = 0; rr < 8; ++rr)
    #pragma unroll
    for (int cc = 0; cc < 4; ++cc) acc[rr][cc] = 0.f;
  const float4* w3f4 = (const float4*)w3;
  for (int kc = 0; kc < 8; ++kc) {
    for (int idx = t; idx < 16*121; idx += 256) w3s[idx] = w3f4[kc*16*121 + idx];
    __syncthreads();
    #pragma unroll
    for (int k4 = 0; k4 < 4; ++k4) {
      float4 wf0 = w3s[(k4*4+0)*121 + tc];
      float4 wf1 = w3s[(k4*4+1)*121 + tc];
      float4 wf2 = w3s[(k4*4+2)*121 + tc];
      float4 wf3 = w3s[(k4*4+3)*121 + tc];
      #pragma unroll
      for (int rr = 0; rr < 8; ++rr) {
        float4 zf = *(const float4*)&z[(tr*8+rr)*DP + kc*16 + k4*4];
        acc[rr][0] = fmaf(zf.x, wf0.x, fmaf(zf.y, wf1.x, fmaf(zf.z, wf2.x, fmaf(zf.w, wf3.x, acc[rr][0]))));
        acc[rr][1] = fmaf(zf.x, wf0.y, fmaf(zf.y, wf1.y, fmaf(zf.z, wf2.y, fmaf(zf.w, wf3.y, acc[rr][1]))));
        acc[rr][2] = fmaf(zf.x, wf0.z, fmaf(zf.y, wf1.z, fmaf(zf.z, wf2.z, fmaf(zf.w, wf3.z, acc[rr][2]))));
        acc[rr][3] = fmaf(zf.x, wf0.w, fmaf(zf.y, wf1.w, fmaf(zf.z, wf2.w, fmaf(zf.w, wf3.w, acc[rr][3]))));
      }
    }
    __syncthreads();
  }
  // epilogue: +b3, relu, zero diagonal, store
  if (tc <= 120) {
    float4 bb = ((const float4*)b3)[tc];
    #pragma unroll
    for (int rr = 0; rr < 8; ++rr) {
      int j = j0 + tr*8 + rr;
      float4 o;
      o.x = fmaxf(acc[rr][0] + bb.x, 0.f);
      o.y = fmaxf(acc[rr][1] + bb.y, 0.f);
      o.z = fmaxf(acc[rr][2] + bb.z, 0.f);
      o.w = fmaxf(acc[rr][3] + bb.w, 0.f);
      if (j == i) { o.x = 0.f; o.y = 0.f; o.z = 0.f; o.w = 0.f; }
      ((float4*)out_eij)[(i*NN + j)*121 + tc] = o;
    }
  }
}

// ---------------------------------------------------------------------------
// Kernel 3: hi[m,i,c] += sum_j eij[i,j,c,msa[m,j]] (msa!=gap); atomicAdd into
// logits (pre-initialized with ei). grid (256 i, 8 j-chunks), block 256.
// thread t: m = t>>1, c-range = (t&1)*11 .. +10
// ---------------------------------------------------------------------------
__global__ __launch_bounds__(256) void k_logits(
    const float* __restrict__ eij, const int* __restrict__ msa_t,
    float* __restrict__ out_log)
{
  __shared__ __align__(16) float4 ebf[121 + 7];
  __shared__ int mcol[MM];
  int i = blockIdx.x, jc = blockIdx.y, t = threadIdx.x;
  int m = t >> 1, half = t & 1, cb = half*11;
  float acc[11];
  #pragma unroll
  for (int q = 0; q < 11; ++q) acc[q] = 0.f;
  const float* eb = (const float*)ebf;
  for (int j = jc*32; j < jc*32 + 32; ++j) {
    if (t < 121) ebf[t] = ((const float4*)eij)[(i*NN + j)*121 + t];
    if (t >= 128 && t < 160) ((int4*)mcol)[t - 128] = ((const int4*)msa_t)[j*32 + (t-128)];
    __syncthreads();
    int d = mcol[m];
    if (d != CC-1) {
      #pragma unroll
      for (int q = 0; q < 11; ++q) acc[q] += eb[(cb + q)*CC + d];
    }
    __syncthreads();
  }
  float* dst = &out_log[(m*NN + i)*CC + cb];
  #pragma unroll
  for (int q = 0; q < 11; ++q) atomicAdd(&dst[q], acc[q]);
}

// ---------------------------------------------------------------------------
extern "C" void kernel_launch(void* const* d_in, const int* in_sizes, int n_in,
                              void* d_out, int out_size, void* d_ws, size_t ws_size,
                              hipStream_t stream) {
  const float* single = (const float*)d_in[0];
  const float* pairp  = (const float*)d_in[1];
  const int*   msa    = (const int*)d_in[2];
  const float* w1  = (const float*)d_in[3];
  const float* b1  = (const float*)d_in[4];
  const float* g1  = (const float*)d_in[5];
  const float* be1 = (const float*)d_in[6];
  const float* w2  = (const float*)d_in[7];
  const float* b2  = (const float*)d_in[8];
  const float* g2  = (const float*)d_in[9];
  const float* be2 = (const float*)d_in[10];
  const float* w3  = (const float*)d_in[11];
  const float* b3  = (const float*)d_in[12];

  float* out = (float*)d_out;
  float* out_eij = out + OUT_EIJ;
  float* out_ei  = out + OUT_EI;
  float* out_log = out + OUT_LOG;
  int* msa_t = (int*)d_ws;   // 128 KB

  // big pair GEMM first
  hipLaunchKernelGGL(k_pair, dim3(16, NN), dim3(256), 0, stream,
                     pairp, g2, be2, w3, b3, out_eij);
  hipLaunchKernelGGL(k_single, dim3(NN), dim3(384), 0, stream,
                     single, w1, b1, g1, be1, w2, b2, out_ei);
  hipLaunchKernelGGL(k_transpose_msa, dim3(NN), dim3(MM), 0, stream, msa, msa_t);
  hipLaunchKernelGGL(k_init_logits, dim3((MM*NN*CC + 255)/256), dim3(256), 0, stream,
                     out_ei, out_log);
  hipLaunchKernelGGL(k_logits, dim3(NN, 8), dim3(256), 0, stream,
                     out_eij, msa_t, out_log);
}

// Round 2
// 331.598 us; speedup vs baseline: 1.9041x; 1.9041x over previous
//
#include <hip/hip_runtime.h>
#include <hip/hip_bf16.h>

#define NN 256
#define MM 128
#define DS 384
#define DP 128
#define CC 22
#define C2 484

#define OUT_EI  (NN*NN*C2)
#define OUT_LOG (OUT_EI + NN*CC)

typedef __attribute__((ext_vector_type(8))) short short8;
typedef __attribute__((ext_vector_type(4))) float f32x4;

__device__ __forceinline__ unsigned f2bf(float x) {
  unsigned u = __float_as_uint(x);
  return (u + 0x7FFFu + ((u >> 16) & 1u)) >> 16;
}

// ---------------------------------------------------------------------------
// pack w3 f32 [128][484] -> bf16 B-fragments in ws:
// frag(kt,ct), lane l, elem e  =  w3[kt*32 + (l>>4)*8 + e][ct*16 + (l&15)]
// stored at w3f[(kt*31 + ct)*64 + l] as 8 bf16 (int4)
// ---------------------------------------------------------------------------
__global__ void k_w3pack(const float* __restrict__ w3, int4* __restrict__ w3f) {
  int ct = blockIdx.x, kt = blockIdx.y, l = threadIdx.x;
  int c = ct * 16 + (l & 15);
  int kb = kt * 32 + (l >> 4) * 8;
  unsigned v[8];
#pragma unroll
  for (int e = 0; e < 8; ++e) {
    float x = (c < C2) ? w3[(kb + e) * C2 + c] : 0.f;
    v[e] = f2bf(x);
  }
  int4 pk;
  pk.x = (int)(v[0] | (v[1] << 16));
  pk.y = (int)(v[2] | (v[3] << 16));
  pk.z = (int)(v[4] | (v[5] << 16));
  pk.w = (int)(v[6] | (v[7] << 16));
  w3f[(kt * 31 + ct) * 64 + l] = pk;
}

// ---------------------------------------------------------------------------
// Fused: per block i (grid 256, block 512 = 8 waves, 64 KB dynamic LDS)
// phase0: single branch -> ei[i,:] (global)
// phase1: zsym -> LN -> bf16 zln LDS [256 j][128 k], 16B-block XOR swizzle
// phase2: MFMA GEMM zln @ w3f -> +b3, relu, diag0 -> eij[i,:,:] (global f32)
// phase3: re-read own eij row (L2-hot), chunk-stage bf16 zE in LDS,
//         MFMA vs in-register one-hot(msa) -> logits[:, i, :] = hi + ei
// ---------------------------------------------------------------------------
extern "C" __global__ __launch_bounds__(512) void k_fused(
    const float* __restrict__ single, const float* __restrict__ pair,
    const int* __restrict__ msa,
    const float* __restrict__ w1, const float* __restrict__ b1,
    const float* __restrict__ g1, const float* __restrict__ be1,
    const float* __restrict__ w2, const float* __restrict__ b2,
    const float* __restrict__ g2, const float* __restrict__ be2,
    const float* __restrict__ b3, const int4* __restrict__ w3f,
    float* __restrict__ outp)
{
  extern __shared__ char smem[];
  float* out_eij = outp;
  float* out_ei  = outp + OUT_EI;
  float* out_log = outp + OUT_LOG;

  const int i = blockIdx.x;
  const int t = threadIdx.x;
  const int w = t >> 6, l = t & 63;
  const int lr = l & 15, lg = l >> 4;

  // ---- phase0 scratch aliases (dead after phase0) ----
  float* srow = (float*)smem;               // [384]
  float* hlx  = (float*)(smem + 1536);      // [384]
  float* part = (float*)(smem + 3072);      // [352]
  float* wred = (float*)(smem + 4480);      // [8]
  float* wredq= (float*)(smem + 4512);      // [8]
  float* mur  = (float*)(smem + 4544);      // [2]

  // ================= phase 0: single branch =================
  if (t < DS) srow[t] = single[i * DS + t];
  __syncthreads();
  float hv = 0.f;
  if (t < DS) {
    float acc = b1[t];
#pragma unroll 8
    for (int d = 0; d < DS; ++d) acc = fmaf(srow[d], w1[d * DS + t], acc);
    hv = 0.5f * acc * (1.0f + erff(acc * 0.70710678118654752f));
    float s = hv, q = hv * hv;
#pragma unroll
    for (int off = 32; off; off >>= 1) { s += __shfl_xor(s, off); q += __shfl_xor(q, off); }
    if ((t & 63) == 0) { wred[t >> 6] = s; wredq[t >> 6] = q; }
  }
  __syncthreads();
  if (t == 0) {
    float S = 0.f, Q = 0.f;
    for (int ww = 0; ww < 6; ++ww) { S += wred[ww]; Q += wredq[ww]; }
    float mu = S / (float)DS;
    mur[0] = mu; mur[1] = rsqrtf(Q / (float)DS - mu * mu + 1e-5f);
  }
  __syncthreads();
  if (t < DS) hlx[t] = (hv - mur[0]) * mur[1] * g1[t] + be1[t];
  __syncthreads();
  if (t < 352) {
    int g = t / 22, c = t - g * 22;
    float p = 0.f;
#pragma unroll
    for (int k = g * 24; k < g * 24 + 24; ++k) p = fmaf(hlx[k], w2[k * CC + c], p);
    part[t] = p;
  }
  __syncthreads();
  if (t < CC) {
    float sm = b2[t];
#pragma unroll
    for (int g = 0; g < 16; ++g) sm += part[g * CC + t];
    out_ei[i * CC + t] = sm;
  }
  __syncthreads();   // phase0 scratch dead; zln writes begin

  // ================= phase 1: zsym -> LN -> bf16 zln LDS =================
  // zln byte addr for (j, k): j*256 + ((k>>3) ^ (j&15))*16 + (k&7)*2
  {
    float2 g2v = ((const float2*)g2)[l];
    float2 bev = ((const float2*)be2)[l];
    for (int it = 0; it < 32; ++it) {
      int j = w * 32 + it;
      float2 a = ((const float2*)(pair + (i * NN + j) * DP))[l];
      float2 b = ((const float2*)(pair + (j * NN + i) * DP))[l];
      float zx = 0.5f * (a.x + b.x), zy = 0.5f * (a.y + b.y);
      float s = zx + zy, q = zx * zx + zy * zy;
#pragma unroll
      for (int off = 32; off; off >>= 1) { s += __shfl_xor(s, off); q += __shfl_xor(q, off); }
      float mu = s * (1.f / 128.f);
      float rs = rsqrtf(q * (1.f / 128.f) - mu * mu + 1e-5f);
      float nx = (zx - mu) * rs * g2v.x + bev.x;
      float ny = (zy - mu) * rs * g2v.y + bev.y;
      unsigned pk = f2bf(nx) | (f2bf(ny) << 16);
      int blk = (l >> 2) ^ (j & 15);           // k=2l -> k>>3 = l>>2
      *(unsigned*)(smem + j * 256 + blk * 16 + (l & 3) * 4) = pk;
    }
  }
  __syncthreads();

  // ================= phase 2: MFMA GEMM -> eij =================
  {
    int jt0 = 2 * w, jt1 = 2 * w + 1;
    short8 a0[4], a1[4];
#pragma unroll
    for (int kt = 0; kt < 4; ++kt) {
      int blk = kt * 4 + lg;
      int j0 = jt0 * 16 + lr;
      int j1 = jt1 * 16 + lr;
      a0[kt] = *(const short8*)(smem + j0 * 256 + (blk ^ (j0 & 15)) * 16);
      a1[kt] = *(const short8*)(smem + j1 * 256 + (blk ^ (j1 & 15)) * 16);
    }
    const short8* w3fv = (const short8*)w3f;
    for (int ct = 0; ct < 31; ++ct) {
      f32x4 acc0 = {0.f, 0.f, 0.f, 0.f}, acc1 = {0.f, 0.f, 0.f, 0.f};
#pragma unroll
      for (int kt = 0; kt < 4; ++kt) {
        short8 bfr = w3fv[(kt * 31 + ct) * 64 + l];
        acc0 = __builtin_amdgcn_mfma_f32_16x16x32_bf16(a0[kt], bfr, acc0, 0, 0, 0);
        acc1 = __builtin_amdgcn_mfma_f32_16x16x32_bf16(a1[kt], bfr, acc1, 0, 0, 0);
      }
      int cflat = ct * 16 + lr;
      if (cflat < C2) {
        float bias = b3[cflat];
#pragma unroll
        for (int r = 0; r < 4; ++r) {
          int j0r = jt0 * 16 + lg * 4 + r;
          float v0 = fmaxf(acc0[r] + bias, 0.f);
          if (j0r == i) v0 = 0.f;
          out_eij[(i * NN + j0r) * C2 + cflat] = v0;
          int j1r = jt1 * 16 + lg * 4 + r;
          float v1 = fmaxf(acc1[r] + bias, 0.f);
          if (j1r == i) v1 = 0.f;
          out_eij[(i * NN + j1r) * C2 + cflat] = v1;
        }
      }
    }
  }
  __threadfence_block();
  __syncthreads();

  // ================= phase 3: coevolution MFMA =================
  // LDS: zE bf16 at [0, 28672): (j, c, d) -> jj*1584 + c*72 + d*2 ; msa_s int[16][128] at 28672
  int* msa_s = (int*)(smem + 28672);
  // zero zE region once (d>=22 slots must be 0.0 bf16 forever)
  for (int idx = t; idx < 28672 / 4; idx += 512) ((unsigned*)smem)[idx] = 0u;
  __syncthreads();

  f32x4 acc[2][2];
#pragma unroll
  for (int a_ = 0; a_ < 2; ++a_)
#pragma unroll
    for (int b_ = 0; b_ < 2; ++b_) acc[a_][b_] = (f32x4){0.f, 0.f, 0.f, 0.f};

  for (int jc = 0; jc < 16; ++jc) {
    // stage msa[m][jc*16 .. +15] -> msa_s[jlocal][m]
    {
      int m = t >> 2, qq = t & 3;
      int4 mv = *(const int4*)(msa + m * NN + jc * 16 + qq * 4);
      msa_s[(qq * 4 + 0) * 128 + m] = mv.x;
      msa_s[(qq * 4 + 1) * 128 + m] = mv.y;
      msa_s[(qq * 4 + 2) * 128 + m] = mv.z;
      msa_s[(qq * 4 + 3) * 128 + m] = mv.w;
    }
    // stage own eij rows -> bf16 zE
    for (int idx = t; idx < 1936; idx += 512) {
      int jj = idx / 121, p = idx - jj * 121;
      float4 v = ((const float4*)(out_eij + (i * NN + jc * 16 + jj) * C2))[p];
      float vv[4] = {v.x, v.y, v.z, v.w};
      int base = 4 * p;
#pragma unroll
      for (int q = 0; q < 4; ++q) {
        int fl = base + q;
        int c = fl / 22, d = fl - c * 22;
        *(unsigned short*)(smem + jj * 1584 + c * 72 + d * 2) = (unsigned short)f2bf(vv[q]);
      }
    }
    __syncthreads();
    if (w < 4) {
#pragma unroll 2
      for (int jj = 0; jj < 16; ++jj) {
#pragma unroll
        for (int cp = 0; cp < 2; ++cp) {
          short8 af = *(const short8*)(smem + jj * 1584 + (cp * 16 + lr) * 72 + lg * 16);
#pragma unroll
          for (int mti = 0; mti < 2; ++mti) {
            int s = msa_s[jj * 128 + (w * 2 + mti) * 16 + lr];
            int rel = s - lg * 8;
            unsigned hval = (s != 21 && ((unsigned)rel) < 8u) ? (0x3F80u << ((rel & 1) << 4)) : 0u;
            int word = rel >> 1;
            union { short8 s8; unsigned u[4]; } bu;
            bu.u[0] = (word == 0) ? hval : 0u;
            bu.u[1] = (word == 1) ? hval : 0u;
            bu.u[2] = (word == 2) ? hval : 0u;
            bu.u[3] = (word == 3) ? hval : 0u;
            acc[mti][cp] = __builtin_amdgcn_mfma_f32_16x16x32_bf16(af, bu.s8, acc[mti][cp], 0, 0, 0);
          }
        }
      }
    }
    __syncthreads();
  }

  // epilogue: logits[m][i][c] = hi + ei[i][c]
  if (w < 4) {
#pragma unroll
    for (int mti = 0; mti < 2; ++mti) {
      int m = (w * 2 + mti) * 16 + lr;
#pragma unroll
      for (int cp = 0; cp < 2; ++cp) {
#pragma unroll
        for (int r = 0; r < 4; ++r) {
          int c = cp * 16 + lg * 4 + r;
          if (c < CC) {
            out_log[(m * NN + i) * CC + c] = acc[mti][cp][r] + out_ei[i * CC + c];
          }
        }
      }
    }
  }
}

// ---------------------------------------------------------------------------
extern "C" void kernel_launch(void* const* d_in, const int* in_sizes, int n_in,
                              void* d_out, int out_size, void* d_ws, size_t ws_size,
                              hipStream_t stream) {
  const float* single = (const float*)d_in[0];
  const float* pairp  = (const float*)d_in[1];
  const int*   msa    = (const int*)d_in[2];
  const float* w1  = (const float*)d_in[3];
  const float* b1  = (const float*)d_in[4];
  const float* g1  = (const float*)d_in[5];
  const float* be1 = (const float*)d_in[6];
  const float* w2  = (const float*)d_in[7];
  const float* b2  = (const float*)d_in[8];
  const float* g2  = (const float*)d_in[9];
  const float* be2 = (const float*)d_in[10];
  const float* w3  = (const float*)d_in[11];
  const float* b3  = (const float*)d_in[12];

  int4* w3f = (int4*)d_ws;   // 124 KB of packed bf16 B-fragments

  hipLaunchKernelGGL(k_w3pack, dim3(31, 4), dim3(64), 0, stream, w3, w3f);
  hipLaunchKernelGGL(k_fused, dim3(256), dim3(512), 65536, stream,
                     single, pairp, msa, w1, b1, g1, be1, w2, b2, g2, be2,
                     b3, (const int4*)w3f, (float*)d_out);
}

// Round 3
// 273.760 us; speedup vs baseline: 2.3064x; 1.2113x over previous
//
#include <hip/hip_runtime.h>
#include <hip/hip_bf16.h>

#define NN 256
#define MM 128
#define DS 384
#define DP 128
#define CC 22
#define C2 484

#define OUT_EI  (NN*NN*C2)
#define OUT_LOG (OUT_EI + NN*CC)

typedef __attribute__((ext_vector_type(8))) short short8;
typedef __attribute__((ext_vector_type(4))) float f32x4;

__device__ __forceinline__ unsigned f2bf(float x) {
  unsigned u = __float_as_uint(x);
  return (u + 0x7FFFu + ((u >> 16) & 1u)) >> 16;
}

// ---------------------------------------------------------------------------
// pack w3 f32 [128][484] -> bf16 B-fragments in ws:
// frag(kt,ct), lane l, elem e  =  w3[kt*32 + (l>>4)*8 + e][ct*16 + (l&15)]
// ---------------------------------------------------------------------------
__global__ void k_w3pack(const float* __restrict__ w3, int4* __restrict__ w3f) {
  int ct = blockIdx.x, kt = blockIdx.y, l = threadIdx.x;
  int c = ct * 16 + (l & 15);
  int kb = kt * 32 + (l >> 4) * 8;
  unsigned v[8];
#pragma unroll
  for (int e = 0; e < 8; ++e) {
    float x = (c < C2) ? w3[(kb + e) * C2 + c] : 0.f;
    v[e] = f2bf(x);
  }
  int4 pk;
  pk.x = (int)(v[0] | (v[1] << 16));
  pk.y = (int)(v[2] | (v[3] << 16));
  pk.z = (int)(v[4] | (v[5] << 16));
  pk.w = (int)(v[6] | (v[7] << 16));
  w3f[(kt * 31 + ct) * 64 + l] = pk;
}

// ---------------------------------------------------------------------------
// transpose msa [128,256] int -> uchar msa_tb [256][128]
// ---------------------------------------------------------------------------
__global__ void k_msat(const int* __restrict__ msa, unsigned char* __restrict__ mt) {
  int j = blockIdx.x, m = threadIdx.x;   // 256 x 128
  mt[j * MM + m] = (unsigned char)msa[m * NN + j];
}

// ---------------------------------------------------------------------------
// single branch -> ei[n,:], plus zero logits[:, n, :]
// ---------------------------------------------------------------------------
__global__ __launch_bounds__(384) void k_single(
    const float* __restrict__ single, const float* __restrict__ w1,
    const float* __restrict__ b1, const float* __restrict__ g1,
    const float* __restrict__ be1, const float* __restrict__ w2,
    const float* __restrict__ b2, float* __restrict__ out_ei,
    float* __restrict__ out_log)
{
  __shared__ float srow[DS];
  __shared__ float hlx[DS];
  __shared__ float part[16 * CC];
  __shared__ float wred[8], wredq[8], mur[2];
  int n = blockIdx.x, t = threadIdx.x;
  srow[t] = single[n * DS + t];
  // zero logits slice while loads are in flight
  for (int idx = t; idx < MM * CC; idx += 384) {
    int m = idx / CC, c = idx - m * CC;
    out_log[(m * NN + n) * CC + c] = 0.f;
  }
  __syncthreads();
  float acc = b1[t];
#pragma unroll 8
  for (int d = 0; d < DS; ++d) acc = fmaf(srow[d], w1[d * DS + t], acc);
  float hv = 0.5f * acc * (1.0f + erff(acc * 0.70710678118654752f));
  float s = hv, q = hv * hv;
#pragma unroll
  for (int off = 32; off; off >>= 1) { s += __shfl_xor(s, off); q += __shfl_xor(q, off); }
  if ((t & 63) == 0) { wred[t >> 6] = s; wredq[t >> 6] = q; }
  __syncthreads();
  if (t == 0) {
    float S = 0.f, Q = 0.f;
    for (int w = 0; w < 6; ++w) { S += wred[w]; Q += wredq[w]; }
    float mu = S / (float)DS;
    mur[0] = mu; mur[1] = rsqrtf(Q / (float)DS - mu * mu + 1e-5f);
  }
  __syncthreads();
  hlx[t] = (hv - mur[0]) * mur[1] * g1[t] + be1[t];
  __syncthreads();
  if (t < 352) {
    int g = t / CC, c = t - g * CC;
    float p = 0.f;
#pragma unroll
    for (int k = g * 24; k < g * 24 + 24; ++k) p = fmaf(hlx[k], w2[k * CC + c], p);
    part[t] = p;
  }
  __syncthreads();
  if (t < CC) {
    float sm = b2[t];
#pragma unroll
    for (int g = 0; g < 16; ++g) sm += part[g * CC + t];
    out_ei[n * CC + t] = sm;
  }
}

// ---------------------------------------------------------------------------
// Fused pair+coevolution. grid (256 i, 2 jh), block 512 (8 waves).
// LDS: zE [0,52224) | msa_s [52224,56320) | zln [56320,64512)
// Per chunk of 32 j: LN->bf16 zln; MFMA zln@w3f -> eij (f32 global + bf16 zE
// from registers); MFMA zE vs in-reg one-hot(msa) -> acc. Epilogue: atomicAdd
// hi (+ei on jh==0) into pre-zeroed logits.
// ---------------------------------------------------------------------------
__global__ __launch_bounds__(512, 4) void k_fused(
    const float* __restrict__ pair, const unsigned char* __restrict__ msa_tb,
    const float* __restrict__ g2, const float* __restrict__ be2,
    const float* __restrict__ b3, const int4* __restrict__ w3f,
    const float* __restrict__ ei,
    float* __restrict__ out_eij, float* __restrict__ out_log)
{
  __shared__ __align__(16) char smem[64512];
  unsigned char* msa_s = (unsigned char*)(smem + 52224);
  char* zln = smem + 56320;

  const int i = blockIdx.x, jh = blockIdx.y;
  const int t = threadIdx.x;
  const int w = t >> 6, l = t & 63;
  const int lr = l & 15, lg = l >> 4;

  // zero zE (pad slots d>=22 / c>=22 must read as 0.0 bf16 forever)
  for (int idx = t; idx < 52224 / 4; idx += 512) ((unsigned*)smem)[idx] = 0u;

  f32x4 acc[2];
  acc[0] = (f32x4){0.f, 0.f, 0.f, 0.f};
  acc[1] = (f32x4){0.f, 0.f, 0.f, 0.f};

  const float2 g2v = ((const float2*)g2)[l];
  const float2 bev = ((const float2*)be2)[l];
  const short8* w3fv = (const short8*)w3f;

  __syncthreads();

  for (int ch = 0; ch < 4; ++ch) {
    const int j0 = jh * 128 + ch * 32;

    // ---- phase1: zsym -> LN -> bf16 zln (wave w: local rows w*4..w*4+3) ----
#pragma unroll
    for (int it = 0; it < 4; ++it) {
      int jl = w * 4 + it;
      int j = j0 + jl;
      float2 a = ((const float2*)(pair + (i * NN + j) * DP))[l];
      float2 b = ((const float2*)(pair + (j * NN + i) * DP))[l];
      float zx = 0.5f * (a.x + b.x), zy = 0.5f * (a.y + b.y);
      float s = zx + zy, q = zx * zx + zy * zy;
#pragma unroll
      for (int off = 32; off; off >>= 1) { s += __shfl_xor(s, off); q += __shfl_xor(q, off); }
      float mu = s * (1.f / 128.f);
      float rs = rsqrtf(q * (1.f / 128.f) - mu * mu + 1e-5f);
      float nx = (zx - mu) * rs * g2v.x + bev.x;
      float ny = (zy - mu) * rs * g2v.y + bev.y;
      unsigned pk = f2bf(nx) | (f2bf(ny) << 16);
      int blk = (l >> 2) ^ (jl & 15);
      *(unsigned*)(zln + jl * 256 + blk * 16 + (l & 3) * 4) = pk;
    }
    // stage msa chunk (contiguous 4KB of transposed table)
    ((uint2*)msa_s)[t] = ((const uint2*)(msa_tb + j0 * MM))[t];
    __syncthreads();

    // ---- phase2: MFMA zln @ w3f -> eij (global f32 + LDS bf16 zE) ----
    short8 a0[4], a1[4];
#pragma unroll
    for (int kt = 0; kt < 4; ++kt) {
      a0[kt] = *(const short8*)(zln + lr * 256 + (((kt * 4 + lg) ^ lr) * 16));
      a1[kt] = *(const short8*)(zln + (16 + lr) * 256 + (((kt * 4 + lg) ^ lr) * 16));
    }
    for (int ct = w; ct < 31; ct += 8) {
      f32x4 c0 = {0.f, 0.f, 0.f, 0.f}, c1 = {0.f, 0.f, 0.f, 0.f};
#pragma unroll
      for (int kt = 0; kt < 4; ++kt) {
        short8 bfr = w3fv[(kt * 31 + ct) * 64 + l];
        c0 = __builtin_amdgcn_mfma_f32_16x16x32_bf16(a0[kt], bfr, c0, 0, 0, 0);
        c1 = __builtin_amdgcn_mfma_f32_16x16x32_bf16(a1[kt], bfr, c1, 0, 0, 0);
      }
      int cflat = ct * 16 + lr;
      if (cflat < C2) {
        float bias = b3[cflat];
        int cdiv = cflat / CC;           // magic-mul
        int dd = cflat - cdiv * CC;
#pragma unroll
        for (int r = 0; r < 4; ++r) {
          int jjl0 = lg * 4 + r;
          int j = j0 + jjl0;
          float v = fmaxf(c0[r] + bias, 0.f);
          if (j == i) v = 0.f;
          out_eij[(i * NN + j) * C2 + cflat] = v;
          *(unsigned short*)(smem + jjl0 * 1584 + cdiv * 72 + dd * 2) = (unsigned short)f2bf(v);

          int jjl1 = 16 + lg * 4 + r;
          j = j0 + jjl1;
          v = fmaxf(c1[r] + bias, 0.f);
          if (j == i) v = 0.f;
          out_eij[(i * NN + j) * C2 + cflat] = v;
          *(unsigned short*)(smem + jjl1 * 1584 + cdiv * 72 + dd * 2) = (unsigned short)f2bf(v);
        }
      }
    }
    __syncthreads();

    // ---- phase3: coevolution MFMA (wave w = m-group w) ----
    for (int jj = 0; jj < 32; ++jj) {
      int s = msa_s[jj * 128 + w * 16 + lr];
      int rel = s - lg * 8;
      unsigned hval = (s != 21 && ((unsigned)rel) < 8u) ? (0x3F80u << ((rel & 1) << 4)) : 0u;
      int word = rel >> 1;
      union { short8 s8; unsigned u[4]; } bu;
      bu.u[0] = (word == 0) ? hval : 0u;
      bu.u[1] = (word == 1) ? hval : 0u;
      bu.u[2] = (word == 2) ? hval : 0u;
      bu.u[3] = (word == 3) ? hval : 0u;
#pragma unroll
      for (int cp = 0; cp < 2; ++cp) {
        short8 af = *(const short8*)(smem + jj * 1584 + (cp * 16 + lr) * 72 + lg * 16);
        acc[cp] = __builtin_amdgcn_mfma_f32_16x16x32_bf16(af, bu.s8, acc[cp], 0, 0, 0);
      }
    }
    __syncthreads();
  }

  // epilogue: atomicAdd hi (+ ei on jh==0)
  {
    int m = w * 16 + lr;
#pragma unroll
    for (int cp = 0; cp < 2; ++cp) {
#pragma unroll
      for (int r = 0; r < 4; ++r) {
        int c = cp * 16 + lg * 4 + r;
        if (c < CC) {
          float add = acc[cp][r] + (jh == 0 ? ei[i * CC + c] : 0.f);
          atomicAdd(&out_log[(m * NN + i) * CC + c], add);
        }
      }
    }
  }
}

// ---------------------------------------------------------------------------
extern "C" void kernel_launch(void* const* d_in, const int* in_sizes, int n_in,
                              void* d_out, int out_size, void* d_ws, size_t ws_size,
                              hipStream_t stream) {
  const float* single = (const float*)d_in[0];
  const float* pairp  = (const float*)d_in[1];
  const int*   msa    = (const int*)d_in[2];
  const float* w1  = (const float*)d_in[3];
  const float* b1  = (const float*)d_in[4];
  const float* g1  = (const float*)d_in[5];
  const float* be1 = (const float*)d_in[6];
  const float* w2  = (const float*)d_in[7];
  const float* b2  = (const float*)d_in[8];
  const float* g2  = (const float*)d_in[9];
  const float* be2 = (const float*)d_in[10];
  const float* w3  = (const float*)d_in[11];
  const float* b3  = (const float*)d_in[12];

  float* out = (float*)d_out;
  float* out_eij = out;
  float* out_ei  = out + OUT_EI;
  float* out_log = out + OUT_LOG;

  int4* w3f = (int4*)d_ws;                                   // 124 KB
  unsigned char* msa_tb = (unsigned char*)d_ws + 131072;     // 32 KB

  hipLaunchKernelGGL(k_w3pack, dim3(31, 4), dim3(64), 0, stream, w3, w3f);
  hipLaunchKernelGGL(k_msat, dim3(NN), dim3(MM), 0, stream, msa, msa_tb);
  hipLaunchKernelGGL(k_single, dim3(NN), dim3(384), 0, stream,
                     single, w1, b1, g1, be1, w2, b2, out_ei, out_log);
  hipLaunchKernelGGL(k_fused, dim3(256, 2), dim3(512), 0, stream,
                     pairp, msa_tb, g2, be2, b3, (const int4*)w3f,
                     out_ei, out_eij, out_log);
}